// Round 1
// baseline (383.699 us; speedup 1.0000x reference)
//
#include <hip/hip_runtime.h>
#include <stdint.h>

#define TOKENS 16384
#define KDIM 1024
#define QKVN 3072

typedef unsigned short u16;
using bf16x8 = __attribute__((ext_vector_type(8))) __bf16;
using f32x4  = __attribute__((ext_vector_type(4))) float;
using u16x8  = __attribute__((ext_vector_type(8))) unsigned short;

__device__ inline u16 f2bf(float f) {
  union { float f; uint32_t u; } v; v.f = f;
  uint32_t u = v.u;
  return (u16)((u + 0x7FFFu + ((u >> 16) & 1u)) >> 16);
}
__device__ inline float bf2f(u16 s) {
  union { uint32_t u; float f; } v; v.u = ((uint32_t)s) << 16;
  return v.f;
}
__device__ inline void g2l16(const void* g, void* l) {
  __builtin_amdgcn_global_load_lds(
      (const __attribute__((address_space(1))) void*)g,
      (__attribute__((address_space(3))) void*)l, 16, 0, 0);
}

// C = A(M x K, bf16 row-major) @ B^T  where B is stored (N x K) bf16 row-major.
// EPI 0: QKV epilogue (phi on cols<2048, mask on K cols), store bf16 to C (ld=3072)
// EPI 1: store fp32 to C (ld=NTOT)
template<int NTOT, int EPI>
__global__ __launch_bounds__(256) void gemm_bt(
    const u16* __restrict__ A, const u16* __restrict__ B,
    void* __restrict__ C, const float* __restrict__ mask) {
  __shared__ u16 Al[128 * 64];
  __shared__ u16 Bl[128 * 64];
  const int t = threadIdx.x;
  const int l = t & 63;
  const int w = t >> 6;
  const int rl = l & 15, kg = l >> 4;
  const int wm = w >> 1, wn = w & 1;
  constexpr int nbn = NTOT / 128;
  constexpr int nwg = (TOKENS / 128) * nbn;
  const int bid = blockIdx.x;
  const int swz = (bid & 7) * (nwg / 8) + (bid >> 3);  // nwg % 8 == 0 (bijective)
  const int bm = swz / nbn, bn = swz % nbn;
  const long ar0 = (long)bm * 128;
  const long br0 = (long)bn * 128;

  f32x4 acc[4][4];
  #pragma unroll
  for (int i = 0; i < 4; ++i)
    #pragma unroll
    for (int j = 0; j < 4; ++j)
      acc[i][j] = (f32x4){0.f, 0.f, 0.f, 0.f};

  for (int k0 = 0; k0 < KDIM; k0 += 64) {
    // stage 128x64 A-tile and 128x64 B-tile; linear LDS dest, XOR-swizzled
    // global source so swizzled ds_reads are conflict-free (guide §5/§6 G4).
    #pragma unroll
    for (int i = 0; i < 4; ++i) {
      int chunk = i * 256 + t;           // 0..1023, wave-linear
      int row = chunk >> 3;
      int scc = (chunk & 7) ^ (row & 7); // source chunk pre-swizzle
      g2l16(A + (ar0 + row) * KDIM + k0 + scc * 8, (char*)Al + chunk * 16);
      g2l16(B + (br0 + row) * KDIM + k0 + scc * 8, (char*)Bl + chunk * 16);
    }
    __syncthreads();
    #pragma unroll
    for (int kk = 0; kk < 2; ++kk) {
      const int kb = kk * 64 + kg * 16;
      bf16x8 af[4], bg[4];
      #pragma unroll
      for (int mi = 0; mi < 4; ++mi) {
        int row = wm * 64 + mi * 16 + rl;
        af[mi] = *(const bf16x8*)((const char*)Al + row * 128 + (kb ^ ((row & 7) << 4)));
      }
      #pragma unroll
      for (int ni = 0; ni < 4; ++ni) {
        int row = wn * 64 + ni * 16 + rl;
        bg[ni] = *(const bf16x8*)((const char*)Bl + row * 128 + (kb ^ ((row & 7) << 4)));
      }
      #pragma unroll
      for (int mi = 0; mi < 4; ++mi)
        #pragma unroll
        for (int ni = 0; ni < 4; ++ni)
          acc[mi][ni] = __builtin_amdgcn_mfma_f32_16x16x32_bf16(af[mi], bg[ni], acc[mi][ni], 0, 0, 0);
    }
    __syncthreads();
  }

  // C/D layout: col = lane&15, row = (lane>>4)*4 + reg (m89-verified)
  #pragma unroll
  for (int mi = 0; mi < 4; ++mi) {
    #pragma unroll
    for (int ni = 0; ni < 4; ++ni) {
      const int col = bn * 128 + wn * 64 + ni * 16 + rl;
      #pragma unroll
      for (int j = 0; j < 4; ++j) {
        const int row = bm * 128 + wm * 64 + mi * 16 + kg * 4 + j;
        float v = acc[mi][ni][j];
        if (EPI == 0) {
          if (col < 2048) {                      // Q or K: phi = elu(x)+1
            v = (v > 0.f) ? (v + 1.f) : __expf(v);
            if (col >= 1024) v *= mask[row];     // K: * mask[token]
          }
          ((u16*)C)[(long)row * QKVN + col] = f2bf(v);
        } else {
          ((float*)C)[(long)row * NTOT + col] = v;
        }
      }
    }
  }
}

// kv[bh][d][e] = sum_n K[n][d] * V[n][e];  ksum[bh][d] = sum_n K[n][d]
// grid: 64 (b,h) * 8 n-splits; fp32 atomic partials into workspace.
__global__ __launch_bounds__(256) void kv_kernel(const u16* __restrict__ QKV,
    float* __restrict__ kvws, float* __restrict__ ksws) {
  __shared__ u16 Kl[32 * 64];
  __shared__ u16 Vl[32 * 64];
  const int t = threadIdx.x;
  const int l = t & 63, w = t >> 6;
  const int rl = l & 15, kg = l >> 4;
  const int bid = blockIdx.x;
  const int bh = bid >> 3, ns = bid & 7;
  const int b = bh >> 4, h = bh & 15;
  const long tok0 = (long)b * 4096 + ns * 512;

  f32x4 acc[4];
  #pragma unroll
  for (int i = 0; i < 4; ++i) acc[i] = (f32x4){0.f, 0.f, 0.f, 0.f};
  float ks = 0.f;
  const int srow = t >> 3, scc = t & 7;

  for (int it = 0; it < 16; ++it) {
    const long tb = tok0 + it * 32;
    g2l16(QKV + (tb + srow) * QKVN + 1024 + h * 64 + scc * 8, (char*)Kl + t * 16);
    g2l16(QKV + (tb + srow) * QKVN + 2048 + h * 64 + scc * 8, (char*)Vl + t * 16);
    __syncthreads();
    union { u16x8 u; bf16x8 v; } au, bu;
    // A = K^T fragment: A[d][n] = K[n][d]; this wave owns d-range [w*16, w*16+16)
    #pragma unroll
    for (int j = 0; j < 8; ++j) au.u[j] = Kl[(kg * 8 + j) * 64 + w * 16 + rl];
    #pragma unroll
    for (int ni = 0; ni < 4; ++ni) {
      #pragma unroll
      for (int j = 0; j < 8; ++j) bu.u[j] = Vl[(kg * 8 + j) * 64 + ni * 16 + rl];
      acc[ni] = __builtin_amdgcn_mfma_f32_16x16x32_bf16(au.v, bu.v, acc[ni], 0, 0, 0);
    }
    #pragma unroll
    for (int r = 0; r < 8; ++r) ks += bf2f(Kl[(w * 8 + r) * 64 + (t & 63)]);
    __syncthreads();
  }
  float* kvb = kvws + bh * 4096;
  #pragma unroll
  for (int ni = 0; ni < 4; ++ni)
    #pragma unroll
    for (int j = 0; j < 4; ++j) {
      const int d = w * 16 + kg * 4 + j;
      const int e = ni * 16 + rl;
      atomicAdd(&kvb[d * 64 + e], acc[ni][j]);
    }
  atomicAdd(&ksws[bh * 64 + (t & 63)], ks);
}

// u[token][h*64+e] = (q . kv[:,e]) / (q . ksum + 1e-6)
__global__ __launch_bounds__(256) void u_kernel(const u16* __restrict__ QKV,
    const float* __restrict__ kvws, const float* __restrict__ ksws,
    u16* __restrict__ U) {
  __shared__ float kvl[4096];
  __shared__ float ksl[64];
  const int t = threadIdx.x;
  const int bid = blockIdx.x;
  const int ht = bid & 15, tt = bid >> 4;
  const int b = tt >> 6;
  const int bh = b * 16 + ht;
  const float* kvg = kvws + bh * 4096;
  #pragma unroll
  for (int i = 0; i < 16; ++i) kvl[i * 256 + t] = kvg[i * 256 + t];
  if (t < 64) ksl[t] = ksws[bh * 64 + t];
  __syncthreads();
  const int token = tt * 64 + (t >> 2);
  const int e0 = (t & 3) * 16;
  const u16* qrow = QKV + (long)token * QKVN + ht * 64;
  float q[64];
  #pragma unroll
  for (int i = 0; i < 8; ++i) {
    u16x8 v = *(const u16x8*)(qrow + i * 8);
    #pragma unroll
    for (int j = 0; j < 8; ++j) q[i * 8 + j] = bf2f(v[j]);
  }
  float norm = 1e-6f;
  float u[16];
  #pragma unroll
  for (int j = 0; j < 16; ++j) u[j] = 0.f;
  #pragma unroll
  for (int d = 0; d < 64; ++d) {
    const float qd = q[d];
    norm += qd * ksl[d];
    const float* kr = &kvl[d * 64 + e0];
    #pragma unroll
    for (int j = 0; j < 16; ++j) u[j] += qd * kr[j];
  }
  const float inv = 1.0f / norm;
  u16* orow = U + (long)token * 1024 + ht * 64 + e0;
  #pragma unroll
  for (int j = 0; j < 16; ++j) orow[j] = f2bf(u[j] * inv);
}

// WqkvT rows 0..1023 = (Wq @ blockdiag(proj))^T, rows 1024..2047 same for Wk
__global__ __launch_bounds__(256) void prep_qk(const float* __restrict__ Wq,
    const float* __restrict__ Wk, const float* __restrict__ proj,
    u16* __restrict__ WqkvT) {
  const int idx = blockIdx.x * 256 + threadIdx.x;  // 2M outputs
  const int c = idx & 1023;
  const int r = idx >> 10;          // 0..2047
  const int m = r >> 10, rr = r & 1023;
  const int h = rr >> 6, j = rr & 63;
  const float* W = m ? Wk : Wq;
  float a = 0.f;
  #pragma unroll 8
  for (int d = 0; d < 64; ++d) a += W[c * 1024 + h * 64 + d] * proj[d * 64 + j];
  WqkvT[(long)r * 1024 + c] = f2bf(a);
}

// WqkvT rows 2048..3071 = Wv^T ;  WoT = Wo^T
__global__ __launch_bounds__(256) void prep_vo(const float* __restrict__ Wv,
    const float* __restrict__ Wo, u16* __restrict__ WqkvT, u16* __restrict__ WoT) {
  const int idx = blockIdx.x * 256 + threadIdx.x;  // 2M
  const int which = idx >> 20;
  const int rc = idx & 1048575;
  const int r = rc >> 10, c = rc & 1023;
  if (which == 0) WqkvT[(long)(2048 + r) * 1024 + c] = f2bf(Wv[c * 1024 + r]);
  else            WoT[(long)r * 1024 + c]            = f2bf(Wo[c * 1024 + r]);
}

__global__ __launch_bounds__(256) void conv_x(const float* __restrict__ x,
                                              u16* __restrict__ xb) {
  const int idx = blockIdx.x * 256 + threadIdx.x;  // 2,097,152 threads * 8 elems
  const float4* p = (const float4*)x + (long)idx * 2;
  const float4 a = p[0], b = p[1];
  u16x8 o;
  o[0] = f2bf(a.x); o[1] = f2bf(a.y); o[2] = f2bf(a.z); o[3] = f2bf(a.w);
  o[4] = f2bf(b.x); o[5] = f2bf(b.y); o[6] = f2bf(b.z); o[7] = f2bf(b.w);
  *((u16x8*)xb + idx) = o;
}

extern "C" void kernel_launch(void* const* d_in, const int* in_sizes, int n_in,
                              void* d_out, int out_size, void* d_ws, size_t ws_size,
                              hipStream_t stream) {
  const float* x    = (const float*)d_in[0];
  const float* mask = (const float*)d_in[1];
  const float* Wq   = (const float*)d_in[2];
  const float* Wk   = (const float*)d_in[3];
  const float* Wv   = (const float*)d_in[4];
  const float* Wo   = (const float*)d_in[5];
  const float* proj = (const float*)d_in[6];

  char* ws = (char*)d_ws;
  u16*  WqkvT = (u16*)(ws);                    // 3072x1024 bf16 = 6 MB
  u16*  WoT   = (u16*)(ws + 6291456);          // 1024x1024 bf16 = 2 MB
  u16*  xb    = (u16*)(ws + 8388608);          // 16384x1024 bf16 = 32 MB (reused as U)
  u16*  QKV   = (u16*)(ws + 41943040);         // 16384x3072 bf16 = 96 MB
  float* kvws = (float*)(ws + 142606336);      // 64*64*64 f32 = 1 MB
  float* ksws = (float*)(ws + 143654912);      // 64*64 f32 = 16 KB
  if (ws_size < (size_t)143671296) return;

  hipMemsetAsync(kvws, 0, 1064960, stream);                       // kv + ksum
  prep_qk<<<8192, 256, 0, stream>>>(Wq, Wk, proj, WqkvT);
  prep_vo<<<8192, 256, 0, stream>>>(Wv, Wo, WqkvT, WoT);
  conv_x <<<8192, 256, 0, stream>>>(x, xb);
  gemm_bt<3072, 0><<<3072, 256, 0, stream>>>(xb, WqkvT, (void*)QKV, mask);
  kv_kernel<<<512, 256, 0, stream>>>(QKV, kvws, ksws);
  u_kernel <<<4096, 256, 0, stream>>>(QKV, kvws, ksws, xb);       // U overwrites xb
  gemm_bt<1024, 1><<<1024, 256, 0, stream>>>(xb, WoT, d_out, nullptr);
}

// Round 2
// 369.896 us; speedup vs baseline: 1.0373x; 1.0373x over previous
//
#include <hip/hip_runtime.h>
#include <stdint.h>

#define TOKENS 16384
#define KDIM 1024
#define QKVN 3072
#define NKT (KDIM / 64)

typedef unsigned short u16;
using bf16x8 = __attribute__((ext_vector_type(8))) __bf16;
using f32x4  = __attribute__((ext_vector_type(4))) float;
using u16x8  = __attribute__((ext_vector_type(8))) unsigned short;

__device__ inline u16 f2bf(float f) {
  union { float f; uint32_t u; } v; v.f = f;
  uint32_t u = v.u;
  return (u16)((u + 0x7FFFu + ((u >> 16) & 1u)) >> 16);
}
__device__ inline float bf2f(u16 s) {
  union { uint32_t u; float f; } v; v.u = ((uint32_t)s) << 16;
  return v.f;
}
__device__ inline void g2l16(const void* g, void* l) {
  __builtin_amdgcn_global_load_lds(
      (const __attribute__((address_space(1))) void*)g,
      (__attribute__((address_space(3))) void*)l, 16, 0, 0);
}

// Stage one 128x64 bf16 half-tile (16 KB): 512 threads x 2 global_load_lds x 16B.
// Linear LDS dest; global source pre-swizzled so swizzled ds_reads are conflict-free.
__device__ inline void stage_half(const u16* __restrict__ g, u16* l, int t) {
  #pragma unroll
  for (int i = 0; i < 2; ++i) {
    const int ch = i * 512 + t;          // 0..1023 chunks of 16B
    const int row = ch >> 3;             // 0..127
    const int cc = (ch & 7) ^ (row & 7); // source chunk pre-swizzle
    g2l16(g + (long)row * KDIM + cc * 8, (char*)l + ch * 16);
  }
}

// One phase: quadrant (MH,NH) of per-wave 128x64 output, full K=64 of current tile.
// 12 ds_read_b128 + 1 half-tile stage + barrier + lgkmcnt(0) + 16 MFMA + barrier.
// vmcnt(4) (2 half-tiles in flight) only at group end, never 0 in the loop (T4).
#define PHASE(MH, NH, STAGE_STMT, GEND) do { \
  bf16x8 af0[4], af1[4], bg0[2], bg1[2]; \
  _Pragma("unroll") \
  for (int mi = 0; mi < 4; ++mi) { \
    const int row = (MH)*128 + wm*64 + mi*16 + rl; \
    const char* p = (const char*)Abuf + row*128; \
    const int sw = (row & 7) << 4; \
    af0[mi] = *(const bf16x8*)(p + ((kg*16) ^ sw)); \
    af1[mi] = *(const bf16x8*)(p + ((64 + kg*16) ^ sw)); \
  } \
  _Pragma("unroll") \
  for (int ni = 0; ni < 2; ++ni) { \
    const int row = (NH)*128 + wn*32 + ni*16 + rl; \
    const char* p = (const char*)Bbuf + row*128; \
    const int sw = (row & 7) << 4; \
    bg0[ni] = *(const bf16x8*)(p + ((kg*16) ^ sw)); \
    bg1[ni] = *(const bf16x8*)(p + ((64 + kg*16) ^ sw)); \
  } \
  STAGE_STMT; \
  __builtin_amdgcn_s_barrier(); \
  asm volatile("s_waitcnt lgkmcnt(0)" ::: "memory"); \
  __builtin_amdgcn_sched_barrier(0); \
  __builtin_amdgcn_s_setprio(1); \
  _Pragma("unroll") \
  for (int mi = 0; mi < 4; ++mi) \
    _Pragma("unroll") \
    for (int ni = 0; ni < 2; ++ni) { \
      acc[(MH)*4+mi][(NH)*2+ni] = __builtin_amdgcn_mfma_f32_16x16x32_bf16( \
          af0[mi], bg0[ni], acc[(MH)*4+mi][(NH)*2+ni], 0, 0, 0); \
      acc[(MH)*4+mi][(NH)*2+ni] = __builtin_amdgcn_mfma_f32_16x16x32_bf16( \
          af1[mi], bg1[ni], acc[(MH)*4+mi][(NH)*2+ni], 0, 0, 0); \
    } \
  __builtin_amdgcn_s_setprio(0); \
  if (GEND) { asm volatile("s_waitcnt vmcnt(4)" ::: "memory"); } \
  __builtin_amdgcn_s_barrier(); \
} while (0)

// C = A(M x K bf16 rm) @ B^T, B stored (N x K) bf16 rm. 256x256 tile, 8-phase.
// EPI 0: QKV epilogue (phi cols<2048, mask on K cols), bf16 C (ld=3072)
// EPI 1: fp32 C (ld=NTOT)
template<int NTOT, int EPI>
__global__ __launch_bounds__(512, 2) void gemm256(
    const u16* __restrict__ A, const u16* __restrict__ Bm,
    void* __restrict__ C, const float* __restrict__ mask) {
  __shared__ u16 lds[2][2][16384];   // [dbuf][A,B][256 rows x 64 cols]
  const int t = threadIdx.x;
  const int l = t & 63;
  const int w = t >> 6;
  const int rl = l & 15, kg = l >> 4;
  const int wm = w >> 2, wn = w & 3;      // 2M x 4N waves
  constexpr int nbn = NTOT / 256;
  constexpr int nwg = (TOKENS / 256) * nbn;
  static_assert(nwg % 8 == 0, "bijective xcd swizzle");
  const int bid = blockIdx.x;
  const int swz = (bid & 7) * (nwg / 8) + (bid >> 3);
  const int bm = swz / nbn, bn = swz % nbn;
  const long ar0 = (long)bm * 256;
  const long br0 = (long)bn * 256;

  f32x4 acc[8][4];
  #pragma unroll
  for (int i = 0; i < 8; ++i)
    #pragma unroll
    for (int j = 0; j < 4; ++j)
      acc[i][j] = (f32x4){0.f, 0.f, 0.f, 0.f};

  // Prologue: tile0 all 4 halves (oldest), then tile1 Ah0/Bh0.
  stage_half(A  + ar0 * KDIM,           &lds[0][0][0],    t);
  stage_half(Bm + br0 * KDIM,           &lds[0][1][0],    t);
  stage_half(A  + (ar0 + 128) * KDIM,   &lds[0][0][8192], t);
  stage_half(Bm + (br0 + 128) * KDIM,   &lds[0][1][8192], t);
  stage_half(A  + ar0 * KDIM + 64,      &lds[1][0][0],    t);
  stage_half(Bm + br0 * KDIM + 64,      &lds[1][1][0],    t);
  asm volatile("s_waitcnt vmcnt(4)" ::: "memory");  // tile0 fully landed
  __builtin_amdgcn_s_barrier();

  for (int kt = 0; kt < NKT; ++kt) {
    const int c = kt & 1;
    // clamp staged tiles at the tail: harmless duplicate data, uniform vmcnt
    const int k1 = ((kt + 1 < NKT) ? (kt + 1) : (NKT - 1)) * 64;
    const int k2 = ((kt + 2 < NKT) ? (kt + 2) : (NKT - 1)) * 64;
    u16* Abuf = &lds[c][0][0];
    u16* Bbuf = &lds[c][1][0];
    u16* Aoth = &lds[c ^ 1][0][0];
    u16* Both = &lds[c ^ 1][1][0];
    // ph1 (0,0): Ah1(t+1) -> other buf (its Ah1 last read in prev group ph4)
    PHASE(0, 0, stage_half(A  + (ar0 + 128) * KDIM + k1, Aoth + 8192, t), 0);
    // ph2 (0,1): Bh1(t+1)
    PHASE(0, 1, stage_half(Bm + (br0 + 128) * KDIM + k1, Both + 8192, t), 0);
    // ph3 (1,0): Ah0(t+2) -> this buf (Ah0 last read at ph2)
    PHASE(1, 0, stage_half(A  + ar0 * KDIM + k2, Abuf, t), 0);
    // ph4 (1,1): Bh0(t+2) (Bh0 last read at ph3); group-end vmcnt(4)
    PHASE(1, 1, stage_half(Bm + br0 * KDIM + k2, Bbuf, t), 1);
  }

  // C/D layout: col = lane&15, row = (lane>>4)*4 + reg
  #pragma unroll
  for (int mh = 0; mh < 2; ++mh)
    #pragma unroll
    for (int nh = 0; nh < 2; ++nh)
      #pragma unroll
      for (int mi = 0; mi < 4; ++mi)
        #pragma unroll
        for (int ni = 0; ni < 2; ++ni) {
          const int col = bn * 256 + nh * 128 + wn * 32 + ni * 16 + rl;
          #pragma unroll
          for (int j = 0; j < 4; ++j) {
            const long row = ar0 + mh * 128 + wm * 64 + mi * 16 + kg * 4 + j;
            float v = acc[mh * 4 + mi][nh * 2 + ni][j];
            if (EPI == 0) {
              if (col < 2048) {                    // Q or K: phi = elu(x)+1
                v = (v > 0.f) ? (v + 1.f) : __expf(v);
                if (col >= 1024) v *= mask[row];   // K: * mask[token]
              }
              ((u16*)C)[row * QKVN + col] = f2bf(v);
            } else {
              ((float*)C)[row * NTOT + col] = v;
            }
          }
        }
}

// kv[bh][d][e] = sum_n K[n][d] * V[n][e];  ksum[bh][d] = sum_n K[n][d]
__global__ __launch_bounds__(256) void kv_kernel(const u16* __restrict__ QKV,
    float* __restrict__ kvws, float* __restrict__ ksws) {
  __shared__ u16 Kl[32 * 64];
  __shared__ u16 Vl[32 * 64];
  const int t = threadIdx.x;
  const int l = t & 63, w = t >> 6;
  const int rl = l & 15, kg = l >> 4;
  const int bid = blockIdx.x;
  const int bh = bid >> 3, ns = bid & 7;
  const int b = bh >> 4, h = bh & 15;
  const long tok0 = (long)b * 4096 + ns * 512;

  f32x4 acc[4];
  #pragma unroll
  for (int i = 0; i < 4; ++i) acc[i] = (f32x4){0.f, 0.f, 0.f, 0.f};
  float ks = 0.f;
  const int srow = t >> 3, scc = t & 7;

  for (int it = 0; it < 16; ++it) {
    const long tb = tok0 + it * 32;
    g2l16(QKV + (tb + srow) * QKVN + 1024 + h * 64 + scc * 8, (char*)Kl + t * 16);
    g2l16(QKV + (tb + srow) * QKVN + 2048 + h * 64 + scc * 8, (char*)Vl + t * 16);
    __syncthreads();
    union { u16x8 u; bf16x8 v; } au, bu;
    #pragma unroll
    for (int j = 0; j < 8; ++j) au.u[j] = Kl[(kg * 8 + j) * 64 + w * 16 + rl];
    #pragma unroll
    for (int ni = 0; ni < 4; ++ni) {
      #pragma unroll
      for (int j = 0; j < 8; ++j) bu.u[j] = Vl[(kg * 8 + j) * 64 + ni * 16 + rl];
      acc[ni] = __builtin_amdgcn_mfma_f32_16x16x32_bf16(au.v, bu.v, acc[ni], 0, 0, 0);
    }
    #pragma unroll
    for (int r = 0; r < 8; ++r) ks += bf2f(Kl[(w * 8 + r) * 64 + (t & 63)]);
    __syncthreads();
  }
  float* kvb = kvws + bh * 4096;
  #pragma unroll
  for (int ni = 0; ni < 4; ++ni)
    #pragma unroll
    for (int j = 0; j < 4; ++j) {
      const int d = w * 16 + kg * 4 + j;
      const int e = ni * 16 + rl;
      atomicAdd(&kvb[d * 64 + e], acc[ni][j]);
    }
  atomicAdd(&ksws[bh * 64 + (t & 63)], ks);
}

// u[token][h*64+e] = (q . kv[:,e]) / (q . ksum + 1e-6)
__global__ __launch_bounds__(256) void u_kernel(const u16* __restrict__ QKV,
    const float* __restrict__ kvws, const float* __restrict__ ksws,
    u16* __restrict__ U) {
  __shared__ float kvl[4096];
  __shared__ float ksl[64];
  const int t = threadIdx.x;
  const int bid = blockIdx.x;
  const int ht = bid & 15, tt = bid >> 4;
  const int b = tt >> 6;
  const int bh = b * 16 + ht;
  const float* kvg = kvws + bh * 4096;
  #pragma unroll
  for (int i = 0; i < 16; ++i) kvl[i * 256 + t] = kvg[i * 256 + t];
  if (t < 64) ksl[t] = ksws[bh * 64 + t];
  __syncthreads();
  const int token = tt * 64 + (t >> 2);
  const int e0 = (t & 3) * 16;
  const u16* qrow = QKV + (long)token * QKVN + ht * 64;
  float q[64];
  #pragma unroll
  for (int i = 0; i < 8; ++i) {
    u16x8 v = *(const u16x8*)(qrow + i * 8);
    #pragma unroll
    for (int j = 0; j < 8; ++j) q[i * 8 + j] = bf2f(v[j]);
  }
  float norm = 1e-6f;
  float u[16];
  #pragma unroll
  for (int j = 0; j < 16; ++j) u[j] = 0.f;
  #pragma unroll
  for (int d = 0; d < 64; ++d) {
    const float qd = q[d];
    norm += qd * ksl[d];
    const float* kr = &kvl[d * 64 + e0];
    #pragma unroll
    for (int j = 0; j < 16; ++j) u[j] += qd * kr[j];
  }
  const float inv = 1.0f / norm;
  u16* orow = U + (long)token * 1024 + ht * 64 + e0;
  #pragma unroll
  for (int j = 0; j < 16; ++j) orow[j] = f2bf(u[j] * inv);
}

// WqkvT rows 0..1023 = (Wq @ blockdiag(proj))^T, rows 1024..2047 same for Wk
__global__ __launch_bounds__(256) void prep_qk(const float* __restrict__ Wq,
    const float* __restrict__ Wk, const float* __restrict__ proj,
    u16* __restrict__ WqkvT) {
  const int idx = blockIdx.x * 256 + threadIdx.x;
  const int c = idx & 1023;
  const int r = idx >> 10;
  const int m = r >> 10, rr = r & 1023;
  const int h = rr >> 6, j = rr & 63;
  const float* W = m ? Wk : Wq;
  float a = 0.f;
  #pragma unroll 8
  for (int d = 0; d < 64; ++d) a += W[c * 1024 + h * 64 + d] * proj[d * 64 + j];
  WqkvT[(long)r * 1024 + c] = f2bf(a);
}

// WqkvT rows 2048..3071 = Wv^T ;  WoT = Wo^T
__global__ __launch_bounds__(256) void prep_vo(const float* __restrict__ Wv,
    const float* __restrict__ Wo, u16* __restrict__ WqkvT, u16* __restrict__ WoT) {
  const int idx = blockIdx.x * 256 + threadIdx.x;
  const int which = idx >> 20;
  const int rc = idx & 1048575;
  const int r = rc >> 10, c = rc & 1023;
  if (which == 0) WqkvT[(long)(2048 + r) * 1024 + c] = f2bf(Wv[c * 1024 + r]);
  else            WoT[(long)r * 1024 + c]            = f2bf(Wo[c * 1024 + r]);
}

__global__ __launch_bounds__(256) void conv_x(const float* __restrict__ x,
                                              u16* __restrict__ xb) {
  const int idx = blockIdx.x * 256 + threadIdx.x;
  const float4* p = (const float4*)x + (long)idx * 2;
  const float4 a = p[0], b = p[1];
  u16x8 o;
  o[0] = f2bf(a.x); o[1] = f2bf(a.y); o[2] = f2bf(a.z); o[3] = f2bf(a.w);
  o[4] = f2bf(b.x); o[5] = f2bf(b.y); o[6] = f2bf(b.z); o[7] = f2bf(b.w);
  *((u16x8*)xb + idx) = o;
}

extern "C" void kernel_launch(void* const* d_in, const int* in_sizes, int n_in,
                              void* d_out, int out_size, void* d_ws, size_t ws_size,
                              hipStream_t stream) {
  const float* x    = (const float*)d_in[0];
  const float* mask = (const float*)d_in[1];
  const float* Wq   = (const float*)d_in[2];
  const float* Wk   = (const float*)d_in[3];
  const float* Wv   = (const float*)d_in[4];
  const float* Wo   = (const float*)d_in[5];
  const float* proj = (const float*)d_in[6];

  char* ws = (char*)d_ws;
  u16*  WqkvT = (u16*)(ws);                    // 3072x1024 bf16 = 6 MB
  u16*  WoT   = (u16*)(ws + 6291456);          // 1024x1024 bf16 = 2 MB
  u16*  xb    = (u16*)(ws + 8388608);          // 16384x1024 bf16 = 32 MB (reused as U)
  u16*  QKV   = (u16*)(ws + 41943040);         // 16384x3072 bf16 = 96 MB
  float* kvws = (float*)(ws + 142606336);      // 64*64*64 f32 = 1 MB
  float* ksws = (float*)(ws + 143654912);      // 64*64 f32 = 16 KB
  if (ws_size < (size_t)143671296) return;

  hipMemsetAsync(kvws, 0, 1064960, stream);
  prep_qk<<<8192, 256, 0, stream>>>(Wq, Wk, proj, WqkvT);
  prep_vo<<<8192, 256, 0, stream>>>(Wv, Wo, WqkvT, WoT);
  conv_x <<<8192, 256, 0, stream>>>(x, xb);
  gemm256<3072, 0><<<768, 512, 0, stream>>>(xb, WqkvT, (void*)QKV, mask);
  kv_kernel<<<512, 256, 0, stream>>>(QKV, kvws, ksws);
  u_kernel <<<4096, 256, 0, stream>>>(QKV, kvws, ksws, xb);
  gemm256<1024, 1><<<256, 512, 0, stream>>>(xb, WoT, d_out, nullptr);
}

// Round 3
// 346.806 us; speedup vs baseline: 1.1064x; 1.0666x over previous
//
#include <hip/hip_runtime.h>
#include <stdint.h>

#define TOKENS 16384
#define KDIM 1024
#define QKVN 3072
#define NKT (KDIM / 64)

typedef unsigned short u16;
using bf16x8 = __attribute__((ext_vector_type(8))) __bf16;
using f32x4  = __attribute__((ext_vector_type(4))) float;
using u16x8  = __attribute__((ext_vector_type(8))) unsigned short;

__device__ inline u16 f2bf(float f) {
  union { float f; uint32_t u; } v; v.f = f;
  uint32_t u = v.u;
  return (u16)((u + 0x7FFFu + ((u >> 16) & 1u)) >> 16);
}
__device__ inline float bf2f(u16 s) {
  union { uint32_t u; float f; } v; v.u = ((uint32_t)s) << 16;
  return v.f;
}
__device__ inline void g2l16(const void* g, void* l) {
  __builtin_amdgcn_global_load_lds(
      (const __attribute__((address_space(1))) void*)g,
      (__attribute__((address_space(3))) void*)l, 16, 0, 0);
}

// Stage one 128x64 bf16 half-tile (16 KB): 512 threads x 2 global_load_lds x 16B.
// Linear LDS dest; global source pre-swizzled so swizzled ds_reads are conflict-free.
__device__ inline void stage_half(const u16* __restrict__ g, u16* l, int t) {
  #pragma unroll
  for (int i = 0; i < 2; ++i) {
    const int ch = i * 512 + t;          // 0..1023 chunks of 16B
    const int row = ch >> 3;             // 0..127
    const int cc = (ch & 7) ^ (row & 7); // source chunk pre-swizzle
    g2l16(g + (long)row * KDIM + cc * 8, (char*)l + ch * 16);
  }
}

// Fragment loads: XOR-swizzled ds_read_b128; DST[x][kh] = k-half kh.
#define LDA(DST, MH) do { \
  _Pragma("unroll") \
  for (int mi = 0; mi < 4; ++mi) { \
    const int row = (MH)*128 + wm*64 + mi*16 + rl; \
    const char* p = (const char*)Abuf + row*128; \
    const int sw = (row & 7) << 4; \
    DST[mi][0] = *(const bf16x8*)(p + ((kg*16) ^ sw)); \
    DST[mi][1] = *(const bf16x8*)(p + ((64 + kg*16) ^ sw)); \
  } \
} while (0)

#define LDB(DST, NH) do { \
  _Pragma("unroll") \
  for (int ni = 0; ni < 2; ++ni) { \
    const int row = (NH)*128 + wn*32 + ni*16 + rl; \
    const char* p = (const char*)Bbuf + row*128; \
    const int sw = (row & 7) << 4; \
    DST[ni][0] = *(const bf16x8*)(p + ((kg*16) ^ sw)); \
    DST[ni][1] = *(const bf16x8*)(p + ((64 + kg*16) ^ sw)); \
  } \
} while (0)

#define MFMAQ(MH, NH, AV, BV) do { \
  __builtin_amdgcn_s_setprio(1); \
  _Pragma("unroll") \
  for (int mi = 0; mi < 4; ++mi) \
    _Pragma("unroll") \
    for (int ni = 0; ni < 2; ++ni) { \
      acc[(MH)*4+mi][(NH)*2+ni] = __builtin_amdgcn_mfma_f32_16x16x32_bf16( \
          AV[mi][0], BV[ni][0], acc[(MH)*4+mi][(NH)*2+ni], 0, 0, 0); \
      acc[(MH)*4+mi][(NH)*2+ni] = __builtin_amdgcn_mfma_f32_16x16x32_bf16( \
          AV[mi][1], BV[ni][1], acc[(MH)*4+mi][(NH)*2+ni], 0, 0, 0); \
    } \
  __builtin_amdgcn_s_setprio(0); \
} while (0)

#define LGKM_WAIT do { \
  asm volatile("s_waitcnt lgkmcnt(0)" ::: "memory"); \
  __builtin_amdgcn_sched_barrier(0); \
} while (0)

// C = A(M x K bf16 rm) @ B^T, B stored (N x K) bf16 rm. 256x256 tile, 8 waves
// (2M x 4N), per-wave 128x64 output in 4 quadrant-phases with register-held
// fragments (24 ds_read_b128 / K-tile / wave, the minimum for this decomposition).
// EPI 0: QKV epilogue (phi cols<2048, mask on K cols), bf16 C (ld=3072)
// EPI 1: fp32 C (ld=NTOT)
template<int NTOT, int EPI>
__global__ __launch_bounds__(512, 2) void gemm256(
    const u16* __restrict__ A, const u16* __restrict__ Bm,
    void* __restrict__ C, const float* __restrict__ mask) {
  __shared__ u16 lds[2][2][16384];   // [dbuf][A,B][256 rows x 64 cols]
  const int t = threadIdx.x;
  const int l = t & 63;
  const int w = t >> 6;
  const int rl = l & 15, kg = l >> 4;
  const int wm = w >> 2, wn = w & 3;      // 2M x 4N waves
  constexpr int nbn = NTOT / 256;
  constexpr int nwg = (TOKENS / 256) * nbn;
  static_assert(nwg % 8 == 0, "bijective xcd swizzle");
  const int bid = blockIdx.x;
  const int swz = (bid & 7) * (nwg / 8) + (bid >> 3);
  const int bm = swz / nbn, bn = swz % nbn;
  const long ar0 = (long)bm * 256;
  const long br0 = (long)bn * 256;

  f32x4 acc[8][4];
  #pragma unroll
  for (int i = 0; i < 8; ++i)
    #pragma unroll
    for (int j = 0; j < 4; ++j)
      acc[i][j] = (f32x4){0.f, 0.f, 0.f, 0.f};

  // Prologue: tile0 all 4 halves (oldest), then tile1 Ah0/Bh0.
  stage_half(A  + ar0 * KDIM,           &lds[0][0][0],    t);
  stage_half(Bm + br0 * KDIM,           &lds[0][1][0],    t);
  stage_half(A  + (ar0 + 128) * KDIM,   &lds[0][0][8192], t);
  stage_half(Bm + (br0 + 128) * KDIM,   &lds[0][1][8192], t);
  stage_half(A  + ar0 * KDIM + 64,      &lds[1][0][0],    t);
  stage_half(Bm + br0 * KDIM + 64,      &lds[1][1][0],    t);
  asm volatile("s_waitcnt vmcnt(4)" ::: "memory");  // tile0 fully landed
  __builtin_amdgcn_s_barrier();

  for (int kt = 0; kt < NKT; ++kt) {
    const int c = kt & 1;
    // clamp staged tiles at the tail: harmless duplicate data, uniform vmcnt
    const int k1 = ((kt + 1 < NKT) ? (kt + 1) : (NKT - 1)) * 64;
    const int k2 = ((kt + 2 < NKT) ? (kt + 2) : (NKT - 1)) * 64;
    u16* Abuf = &lds[c][0][0];
    u16* Bbuf = &lds[c][1][0];
    u16* Aoth = &lds[c ^ 1][0][0];
    u16* Both = &lds[c ^ 1][1][0];
    bf16x8 a_[4][2], b0_[2][2], b1_[2][2];

    // ph1 Q00: read A[mh0] (8) + B[nh0] (4); stage Ah1(t+1) -> other buf
    LDA(a_, 0); LDB(b0_, 0);
    stage_half(A + (ar0 + 128) * KDIM + k1, Aoth + 8192, t);
    __builtin_amdgcn_s_barrier();
    LGKM_WAIT;
    MFMAQ(0, 0, a_, b0_);
    __builtin_amdgcn_s_barrier();

    // ph2 Q01: read B[nh1] (4); stage Bh1(t+1) -> other buf
    LDB(b1_, 1);
    stage_half(Bm + (br0 + 128) * KDIM + k1, Both + 8192, t);
    __builtin_amdgcn_s_barrier();
    LGKM_WAIT;
    MFMAQ(0, 1, a_, b1_);
    __builtin_amdgcn_s_barrier();

    // ph3 Q10: read A[mh1] (8, reuse regs); stage Ah0(t+2) -> this buf
    LDA(a_, 1);
    stage_half(A + ar0 * KDIM + k2, Abuf, t);
    __builtin_amdgcn_s_barrier();
    LGKM_WAIT;
    MFMAQ(1, 0, a_, b0_);
    __builtin_amdgcn_s_barrier();

    // ph4 Q11: no reads; stage Bh0(t+2); group-end counted vmcnt(4)
    stage_half(Bm + br0 * KDIM + k2, Bbuf, t);
    __builtin_amdgcn_s_barrier();
    MFMAQ(1, 1, a_, b1_);
    asm volatile("s_waitcnt vmcnt(4)" ::: "memory");
    __builtin_amdgcn_s_barrier();
  }
  asm volatile("s_waitcnt vmcnt(0)" ::: "memory");  // drain before wave exit

  // C/D layout: col = lane&15, row = (lane>>4)*4 + reg
  #pragma unroll
  for (int mh = 0; mh < 2; ++mh)
    #pragma unroll
    for (int nh = 0; nh < 2; ++nh)
      #pragma unroll
      for (int mi = 0; mi < 4; ++mi)
        #pragma unroll
        for (int ni = 0; ni < 2; ++ni) {
          const int col = bn * 256 + nh * 128 + wn * 32 + ni * 16 + rl;
          #pragma unroll
          for (int j = 0; j < 4; ++j) {
            const long row = ar0 + mh * 128 + wm * 64 + mi * 16 + kg * 4 + j;
            float v = acc[mh * 4 + mi][nh * 2 + ni][j];
            if (EPI == 0) {
              if (col < 2048) {                    // Q or K: phi = elu(x)+1
                v = (v > 0.f) ? (v + 1.f) : __expf(v);
                if (col >= 1024) v *= mask[row];   // K: * mask[token]
              }
              ((u16*)C)[row * QKVN + col] = f2bf(v);
            } else {
              ((float*)C)[row * NTOT + col] = v;
            }
          }
        }
}

// kv[bh][d][e] = sum_n K[n][d] * V[n][e];  ksum[bh][d] = sum_n K[n][d]
__global__ __launch_bounds__(256) void kv_kernel(const u16* __restrict__ QKV,
    float* __restrict__ kvws, float* __restrict__ ksws) {
  __shared__ u16 Kl[32 * 64];
  __shared__ u16 Vl[32 * 64];
  const int t = threadIdx.x;
  const int l = t & 63, w = t >> 6;
  const int rl = l & 15, kg = l >> 4;
  const int bid = blockIdx.x;
  const int bh = bid >> 3, ns = bid & 7;
  const int b = bh >> 4, h = bh & 15;
  const long tok0 = (long)b * 4096 + ns * 512;

  f32x4 acc[4];
  #pragma unroll
  for (int i = 0; i < 4; ++i) acc[i] = (f32x4){0.f, 0.f, 0.f, 0.f};
  float ks = 0.f;
  const int srow = t >> 3, scc = t & 7;

  for (int it = 0; it < 16; ++it) {
    const long tb = tok0 + it * 32;
    g2l16(QKV + (tb + srow) * QKVN + 1024 + h * 64 + scc * 8, (char*)Kl + t * 16);
    g2l16(QKV + (tb + srow) * QKVN + 2048 + h * 64 + scc * 8, (char*)Vl + t * 16);
    __syncthreads();
    union { u16x8 u; bf16x8 v; } au, bu;
    #pragma unroll
    for (int j = 0; j < 8; ++j) au.u[j] = Kl[(kg * 8 + j) * 64 + w * 16 + rl];
    #pragma unroll
    for (int ni = 0; ni < 4; ++ni) {
      #pragma unroll
      for (int j = 0; j < 8; ++j) bu.u[j] = Vl[(kg * 8 + j) * 64 + ni * 16 + rl];
      acc[ni] = __builtin_amdgcn_mfma_f32_16x16x32_bf16(au.v, bu.v, acc[ni], 0, 0, 0);
    }
    #pragma unroll
    for (int r = 0; r < 8; ++r) ks += bf2f(Kl[(w * 8 + r) * 64 + (t & 63)]);
    __syncthreads();
  }
  float* kvb = kvws + bh * 4096;
  #pragma unroll
  for (int ni = 0; ni < 4; ++ni)
    #pragma unroll
    for (int j = 0; j < 4; ++j) {
      const int d = w * 16 + kg * 4 + j;
      const int e = ni * 16 + rl;
      atomicAdd(&kvb[d * 64 + e], acc[ni][j]);
    }
  atomicAdd(&ksws[bh * 64 + (t & 63)], ks);
}

// u[token][h*64+e] = (q . kv[:,e]) / (q . ksum + 1e-6)
__global__ __launch_bounds__(256) void u_kernel(const u16* __restrict__ QKV,
    const float* __restrict__ kvws, const float* __restrict__ ksws,
    u16* __restrict__ U) {
  __shared__ float kvl[4096];
  __shared__ float ksl[64];
  const int t = threadIdx.x;
  const int bid = blockIdx.x;
  const int ht = bid & 15, tt = bid >> 4;
  const int b = tt >> 6;
  const int bh = b * 16 + ht;
  const float* kvg = kvws + bh * 4096;
  #pragma unroll
  for (int i = 0; i < 16; ++i) kvl[i * 256 + t] = kvg[i * 256 + t];
  if (t < 64) ksl[t] = ksws[bh * 64 + t];
  __syncthreads();
  const int token = tt * 64 + (t >> 2);
  const int e0 = (t & 3) * 16;
  const u16* qrow = QKV + (long)token * QKVN + ht * 64;
  float q[64];
  #pragma unroll
  for (int i = 0; i < 8; ++i) {
    u16x8 v = *(const u16x8*)(qrow + i * 8);
    #pragma unroll
    for (int j = 0; j < 8; ++j) q[i * 8 + j] = bf2f(v[j]);
  }
  float norm = 1e-6f;
  float u[16];
  #pragma unroll
  for (int j = 0; j < 16; ++j) u[j] = 0.f;
  #pragma unroll
  for (int d = 0; d < 64; ++d) {
    const float qd = q[d];
    norm += qd * ksl[d];
    const float* kr = &kvl[d * 64 + e0];
    #pragma unroll
    for (int j = 0; j < 16; ++j) u[j] += qd * kr[j];
  }
  const float inv = 1.0f / norm;
  u16* orow = U + (long)token * 1024 + ht * 64 + e0;
  #pragma unroll
  for (int j = 0; j < 16; ++j) orow[j] = f2bf(u[j] * inv);
}

// WqkvT rows 0..1023 = (Wq @ blockdiag(proj))^T, rows 1024..2047 same for Wk
__global__ __launch_bounds__(256) void prep_qk(const float* __restrict__ Wq,
    const float* __restrict__ Wk, const float* __restrict__ proj,
    u16* __restrict__ WqkvT) {
  const int idx = blockIdx.x * 256 + threadIdx.x;
  const int c = idx & 1023;
  const int r = idx >> 10;
  const int m = r >> 10, rr = r & 1023;
  const int h = rr >> 6, j = rr & 63;
  const float* W = m ? Wk : Wq;
  float a = 0.f;
  #pragma unroll 8
  for (int d = 0; d < 64; ++d) a += W[c * 1024 + h * 64 + d] * proj[d * 64 + j];
  WqkvT[(long)r * 1024 + c] = f2bf(a);
}

// WqkvT rows 2048..3071 = Wv^T ;  WoT = Wo^T
__global__ __launch_bounds__(256) void prep_vo(const float* __restrict__ Wv,
    const float* __restrict__ Wo, u16* __restrict__ WqkvT, u16* __restrict__ WoT) {
  const int idx = blockIdx.x * 256 + threadIdx.x;
  const int which = idx >> 20;
  const int rc = idx & 1048575;
  const int r = rc >> 10, c = rc & 1023;
  if (which == 0) WqkvT[(long)(2048 + r) * 1024 + c] = f2bf(Wv[c * 1024 + r]);
  else            WoT[(long)r * 1024 + c]            = f2bf(Wo[c * 1024 + r]);
}

__global__ __launch_bounds__(256) void conv_x(const float* __restrict__ x,
                                              u16* __restrict__ xb) {
  const int idx = blockIdx.x * 256 + threadIdx.x;
  const float4* p = (const float4*)x + (long)idx * 2;
  const float4 a = p[0], b = p[1];
  u16x8 o;
  o[0] = f2bf(a.x); o[1] = f2bf(a.y); o[2] = f2bf(a.z); o[3] = f2bf(a.w);
  o[4] = f2bf(b.x); o[5] = f2bf(b.y); o[6] = f2bf(b.z); o[7] = f2bf(b.w);
  *((u16x8*)xb + idx) = o;
}

extern "C" void kernel_launch(void* const* d_in, const int* in_sizes, int n_in,
                              void* d_out, int out_size, void* d_ws, size_t ws_size,
                              hipStream_t stream) {
  const float* x    = (const float*)d_in[0];
  const float* mask = (const float*)d_in[1];
  const float* Wq   = (const float*)d_in[2];
  const float* Wk   = (const float*)d_in[3];
  const float* Wv   = (const float*)d_in[4];
  const float* Wo   = (const float*)d_in[5];
  const float* proj = (const float*)d_in[6];

  char* ws = (char*)d_ws;
  u16*  WqkvT = (u16*)(ws);                    // 3072x1024 bf16 = 6 MB
  u16*  WoT   = (u16*)(ws + 6291456);          // 1024x1024 bf16 = 2 MB
  u16*  xb    = (u16*)(ws + 8388608);          // 16384x1024 bf16 = 32 MB (reused as U)
  u16*  QKV   = (u16*)(ws + 41943040);         // 16384x3072 bf16 = 96 MB
  float* kvws = (float*)(ws + 142606336);      // 64*64*64 f32 = 1 MB
  float* ksws = (float*)(ws + 143654912);      // 64*64 f32 = 16 KB
  if (ws_size < (size_t)143671296) return;

  hipMemsetAsync(kvws, 0, 1064960, stream);
  prep_qk<<<8192, 256, 0, stream>>>(Wq, Wk, proj, WqkvT);
  prep_vo<<<8192, 256, 0, stream>>>(Wv, Wo, WqkvT, WoT);
  conv_x <<<8192, 256, 0, stream>>>(x, xb);
  gemm256<3072, 0><<<768, 512, 0, stream>>>(xb, WqkvT, (void*)QKV, mask);
  kv_kernel<<<512, 256, 0, stream>>>(QKV, kvws, ksws);
  u_kernel <<<4096, 256, 0, stream>>>(QKV, kvws, ksws, xb);
  gemm256<1024, 1><<<256, 512, 0, stream>>>(xb, WoT, d_out, nullptr);
}

// Round 4
// 282.097 us; speedup vs baseline: 1.3602x; 1.2294x over previous
//
#include <hip/hip_runtime.h>
#include <stdint.h>

#define TOKENS 16384
#define KDIM 1024
#define QKVN 3072
#define NKT (KDIM / 64)

typedef unsigned short u16;
using bf16x8 = __attribute__((ext_vector_type(8))) __bf16;
using f32x4  = __attribute__((ext_vector_type(4))) float;
using u16x8  = __attribute__((ext_vector_type(8))) unsigned short;

__device__ inline u16 f2bf(float f) {
  union { float f; uint32_t u; } v; v.f = f;
  uint32_t u = v.u;
  return (u16)((u + 0x7FFFu + ((u >> 16) & 1u)) >> 16);
}
__device__ inline float bf2f(u16 s) {
  union { uint32_t u; float f; } v; v.u = ((uint32_t)s) << 16;
  return v.f;
}
__device__ inline void g2l16(const void* g, void* l) {
  __builtin_amdgcn_global_load_lds(
      (const __attribute__((address_space(1))) void*)g,
      (__attribute__((address_space(3))) void*)l, 16, 0, 0);
}

// Stage one 128x64 bf16 half-tile (16 KB): 512 threads x 2 global_load_lds x 16B.
// Linear LDS dest; global source pre-swizzled so swizzled ds_reads are conflict-free.
__device__ inline void stage_half(const u16* __restrict__ g, u16* l, int t) {
  #pragma unroll
  for (int i = 0; i < 2; ++i) {
    const int ch = i * 512 + t;          // 0..1023 chunks of 16B
    const int row = ch >> 3;             // 0..127
    const int cc = (ch & 7) ^ (row & 7); // source chunk pre-swizzle
    g2l16(g + (long)row * KDIM + cc * 8, (char*)l + ch * 16);
  }
}

// Fragment loads from a 128x64 half (16 KB) at BASE; XOR-swizzled ds_read_b128.
#define LDA_H(DST, BASE) do { \
  _Pragma("unroll") \
  for (int mi = 0; mi < 4; ++mi) { \
    const int row = wm*64 + mi*16 + rl; \
    const char* p = (const char*)(BASE) + row*128; \
    const int sw = (row & 7) << 4; \
    DST[mi][0] = *(const bf16x8*)(p + ((kg*16) ^ sw)); \
    DST[mi][1] = *(const bf16x8*)(p + ((64 + kg*16) ^ sw)); \
  } \
} while (0)

#define LDB_H(DST, BASE) do { \
  _Pragma("unroll") \
  for (int ni = 0; ni < 2; ++ni) { \
    const int row = wn*32 + ni*16 + rl; \
    const char* p = (const char*)(BASE) + row*128; \
    const int sw = (row & 7) << 4; \
    DST[ni][0] = *(const bf16x8*)(p + ((kg*16) ^ sw)); \
    DST[ni][1] = *(const bf16x8*)(p + ((64 + kg*16) ^ sw)); \
  } \
} while (0)

#define MFMAQ(MH, NH, AV, BV) do { \
  __builtin_amdgcn_s_setprio(1); \
  _Pragma("unroll") \
  for (int mi = 0; mi < 4; ++mi) \
    _Pragma("unroll") \
    for (int ni = 0; ni < 2; ++ni) { \
      acc[(MH)*4+mi][(NH)*2+ni] = __builtin_amdgcn_mfma_f32_16x16x32_bf16( \
          AV[mi][0], BV[ni][0], acc[(MH)*4+mi][(NH)*2+ni], 0, 0, 0); \
      acc[(MH)*4+mi][(NH)*2+ni] = __builtin_amdgcn_mfma_f32_16x16x32_bf16( \
          AV[mi][1], BV[ni][1], acc[(MH)*4+mi][(NH)*2+ni], 0, 0, 0); \
    } \
  __builtin_amdgcn_s_setprio(0); \
} while (0)

#define LGKM(N) do { \
  asm volatile("s_waitcnt lgkmcnt(" #N ")" ::: "memory"); \
  __builtin_amdgcn_sched_barrier(0); \
} while (0)
#define VMC(N) asm volatile("s_waitcnt vmcnt(" #N ")" ::: "memory")
#define BAR() __builtin_amdgcn_s_barrier()

// C = A(M x K bf16 rm) @ B^T, B stored (N x K) bf16 rm. 256x256 tile, 8 waves
// (2M x 4N). Pipelined 4-phase/K-tile schedule: phase p issues ds_reads for
// phase p+1's operands (counted lgkmcnt drains only the PREVIOUS phase's
// reads -> reads hide under MFMA). 1 half-tile staged per phase, 2 tiles
// ahead; vmcnt(8) per phase keeps 4 stage-phases in flight (never drain 0).
// EPI 0: QKV epilogue (phi cols<2048, mask on K cols), bf16 C (ld=3072)
// EPI 1: fp32 C (ld=NTOT)
template<int NTOT, int EPI>
__global__ __launch_bounds__(512, 2) void gemm256(
    const u16* __restrict__ A, const u16* __restrict__ Bm,
    void* __restrict__ C, const float* __restrict__ mask) {
  __shared__ u16 lds[2][2][16384];   // [dbuf][A,B][2 halves x 128 rows x 64 cols]
  const int t = threadIdx.x;
  const int l = t & 63;
  const int w = t >> 6;
  const int rl = l & 15, kg = l >> 4;
  const int wm = w >> 2, wn = w & 3;      // 2M x 4N waves
  constexpr int nbn = NTOT / 256;
  constexpr int nwg = (TOKENS / 256) * nbn;
  static_assert(nwg % 8 == 0, "bijective xcd swizzle");
  const int bid = blockIdx.x;
  const int swz = (bid & 7) * (nwg / 8) + (bid >> 3);
  const int bm = swz / nbn, bn = swz % nbn;
  const long ar0 = (long)bm * 256;
  const long br0 = (long)bn * 256;

  f32x4 acc[8][4];
  #pragma unroll
  for (int i = 0; i < 8; ++i)
    #pragma unroll
    for (int j = 0; j < 4; ++j)
      acc[i][j] = (f32x4){0.f, 0.f, 0.f, 0.f};

  bf16x8 Ar0[4][2], Ar1[4][2], Br0[2][2], Br1[2][2];

  // Prologue: stage tiles 0,1 in steady-state FIFO order [Ah0,Bh0,Bh1,Ah1].
  stage_half(A  + ar0 * KDIM,              &lds[0][0][0],    t);
  stage_half(Bm + br0 * KDIM,              &lds[0][1][0],    t);
  stage_half(Bm + (br0 + 128) * KDIM,      &lds[0][1][8192], t);
  stage_half(A  + (ar0 + 128) * KDIM,      &lds[0][0][8192], t);
  stage_half(A  + ar0 * KDIM + 64,         &lds[1][0][0],    t);
  stage_half(Bm + br0 * KDIM + 64,         &lds[1][1][0],    t);
  stage_half(Bm + (br0 + 128) * KDIM + 64, &lds[1][1][8192], t);
  stage_half(A  + (ar0 + 128) * KDIM + 64, &lds[1][0][8192], t);
  VMC(8);                       // tile0's 8 loads landed
  BAR();
  LDA_H(Ar0, &lds[0][0][0]);    // pre-read A0(0), B0(0)
  LDB_H(Br0, &lds[0][1][0]);
  LGKM(0);
  BAR();                        // pre-reads complete before ph0's overwrite-stage

  for (int kt = 0; kt < NKT; ++kt) {
    const int c = kt & 1, nb = c ^ 1;
    const int k2 = ((kt + 2 < NKT) ? (kt + 2) : (NKT - 1)) * 64;

    // ph0: MFMA Q00(Ar0,Br0); read Br1 <- Bh1(t); stage Ah0(t+2) -> buf c
    LDB_H(Br1, &lds[c][1][8192]);
    stage_half(A + ar0 * KDIM + k2, &lds[c][0][0], t);
    BAR();
    LGKM(4);                    // drains prev-ph3's Br0 reads; leaves Br1
    MFMAQ(0, 0, Ar0, Br0);
    VMC(8);
    BAR();

    // ph1: MFMA Q01(Ar0,Br1); read Ar1 <- Ah1(t); stage Bh0(t+2) -> buf c
    LDA_H(Ar1, &lds[c][0][8192]);
    stage_half(Bm + br0 * KDIM + k2, &lds[c][1][0], t);
    BAR();
    LGKM(8);                    // drains Br1; leaves Ar1
    MFMAQ(0, 1, Ar0, Br1);
    VMC(8);
    BAR();

    // ph2: MFMA Q10(Ar1,Br0); read Ar0 <- Ah0(t+1)@other; stage Bh1(t+2) -> buf c
    LDA_H(Ar0, &lds[nb][0][0]);
    stage_half(Bm + (br0 + 128) * KDIM + k2, &lds[c][1][8192], t);
    BAR();
    LGKM(8);                    // drains Ar1; leaves new Ar0
    MFMAQ(1, 0, Ar1, Br0);
    VMC(8);
    BAR();

    // ph3: MFMA Q11(Ar1,Br1); read Br0 <- Bh0(t+1)@other; stage Ah1(t+2) -> buf c
    LDB_H(Br0, &lds[nb][1][0]);
    stage_half(A + (ar0 + 128) * KDIM + k2, &lds[c][0][8192], t);
    BAR();
    LGKM(4);                    // drains new Ar0; leaves new Br0
    MFMAQ(1, 1, Ar1, Br1);
    VMC(8);
    BAR();
  }
  VMC(0);                       // drain stages before wave exit

  // C/D layout: col = lane&15, row = (lane>>4)*4 + reg
  #pragma unroll
  for (int mh = 0; mh < 2; ++mh)
    #pragma unroll
    for (int nh = 0; nh < 2; ++nh)
      #pragma unroll
      for (int mi = 0; mi < 4; ++mi)
        #pragma unroll
        for (int ni = 0; ni < 2; ++ni) {
          const int col = bn * 256 + nh * 128 + wn * 32 + ni * 16 + rl;
          #pragma unroll
          for (int j = 0; j < 4; ++j) {
            const long row = ar0 + mh * 128 + wm * 64 + mi * 16 + kg * 4 + j;
            float v = acc[mh * 4 + mi][nh * 2 + ni][j];
            if (EPI == 0) {
              if (col < 2048) {                    // Q or K: phi = elu(x)+1
                v = (v > 0.f) ? (v + 1.f) : __expf(v);
                if (col >= 1024) v *= mask[row];   // K: * mask[token]
              }
              ((u16*)C)[row * QKVN + col] = f2bf(v);
            } else {
              ((float*)C)[row * NTOT + col] = v;
            }
          }
        }
}

// kv[bh][d][e] = sum_n K[n][d] * V[n][e];  ksum[bh][d] = sum_n K[n][d]
__global__ __launch_bounds__(256) void kv_kernel(const u16* __restrict__ QKV,
    float* __restrict__ kvws, float* __restrict__ ksws) {
  __shared__ u16 Kl[32 * 64];
  __shared__ u16 Vl[32 * 64];
  const int t = threadIdx.x;
  const int l = t & 63, w = t >> 6;
  const int rl = l & 15, kg = l >> 4;
  const int bid = blockIdx.x;
  const int bh = bid >> 3, ns = bid & 7;
  const int b = bh >> 4, h = bh & 15;
  const long tok0 = (long)b * 4096 + ns * 512;

  f32x4 acc[4];
  #pragma unroll
  for (int i = 0; i < 4; ++i) acc[i] = (f32x4){0.f, 0.f, 0.f, 0.f};
  float ks = 0.f;
  const int srow = t >> 3, scc = t & 7;

  for (int it = 0; it < 16; ++it) {
    const long tb = tok0 + it * 32;
    g2l16(QKV + (tb + srow) * QKVN + 1024 + h * 64 + scc * 8, (char*)Kl + t * 16);
    g2l16(QKV + (tb + srow) * QKVN + 2048 + h * 64 + scc * 8, (char*)Vl + t * 16);
    __syncthreads();
    union { u16x8 u; bf16x8 v; } au, bu;
    #pragma unroll
    for (int j = 0; j < 8; ++j) au.u[j] = Kl[(kg * 8 + j) * 64 + w * 16 + rl];
    #pragma unroll
    for (int ni = 0; ni < 4; ++ni) {
      #pragma unroll
      for (int j = 0; j < 8; ++j) bu.u[j] = Vl[(kg * 8 + j) * 64 + ni * 16 + rl];
      acc[ni] = __builtin_amdgcn_mfma_f32_16x16x32_bf16(au.v, bu.v, acc[ni], 0, 0, 0);
    }
    #pragma unroll
    for (int r = 0; r < 8; ++r) ks += bf2f(Kl[(w * 8 + r) * 64 + (t & 63)]);
    __syncthreads();
  }
  float* kvb = kvws + bh * 4096;
  #pragma unroll
  for (int ni = 0; ni < 4; ++ni)
    #pragma unroll
    for (int j = 0; j < 4; ++j) {
      const int d = w * 16 + kg * 4 + j;
      const int e = ni * 16 + rl;
      atomicAdd(&kvb[d * 64 + e], acc[ni][j]);
    }
  atomicAdd(&ksws[bh * 64 + (t & 63)], ks);
}

// u[token][h*64+e] = (q . kv[:,e]) / (q . ksum + 1e-6)
__global__ __launch_bounds__(256) void u_kernel(const u16* __restrict__ QKV,
    const float* __restrict__ kvws, const float* __restrict__ ksws,
    u16* __restrict__ U) {
  __shared__ float kvl[4096];
  __shared__ float ksl[64];
  const int t = threadIdx.x;
  const int bid = blockIdx.x;
  const int ht = bid & 15, tt = bid >> 4;
  const int b = tt >> 6;
  const int bh = b * 16 + ht;
  const float* kvg = kvws + bh * 4096;
  #pragma unroll
  for (int i = 0; i < 16; ++i) kvl[i * 256 + t] = kvg[i * 256 + t];
  if (t < 64) ksl[t] = ksws[bh * 64 + t];
  __syncthreads();
  const int token = tt * 64 + (t >> 2);
  const int e0 = (t & 3) * 16;
  const u16* qrow = QKV + (long)token * QKVN + ht * 64;
  float q[64];
  #pragma unroll
  for (int i = 0; i < 8; ++i) {
    u16x8 v = *(const u16x8*)(qrow + i * 8);
    #pragma unroll
    for (int j = 0; j < 8; ++j) q[i * 8 + j] = bf2f(v[j]);
  }
  float norm = 1e-6f;
  float u[16];
  #pragma unroll
  for (int j = 0; j < 16; ++j) u[j] = 0.f;
  #pragma unroll
  for (int d = 0; d < 64; ++d) {
    const float qd = q[d];
    norm += qd * ksl[d];
    const float* kr = &kvl[d * 64 + e0];
    #pragma unroll
    for (int j = 0; j < 16; ++j) u[j] += qd * kr[j];
  }
  const float inv = 1.0f / norm;
  u16* orow = U + (long)token * 1024 + ht * 64 + e0;
  #pragma unroll
  for (int j = 0; j < 16; ++j) orow[j] = f2bf(u[j] * inv);
}

// WqkvT rows 0..2047 = (W{q,k} @ blockdiag(proj))^T. LDS-staged, coalesced.
// grid: m(2) x h(16) x cb(8) = 256 blocks
__global__ __launch_bounds__(256) void prep_qk(const float* __restrict__ Wq,
    const float* __restrict__ Wk, const float* __restrict__ proj,
    u16* __restrict__ WqkvT) {
  __shared__ float Wl[128][65];
  __shared__ float Pl[64][65];
  const int bid = blockIdx.x;
  const int m = bid >> 7, h = (bid >> 3) & 15, cb = bid & 7;
  const float* W = m ? Wk : Wq;
  const int t = threadIdx.x;
  #pragma unroll
  for (int i = 0; i < 16; ++i) {
    const int idx = i * 256 + t;
    Pl[idx >> 6][idx & 63] = proj[idx];
  }
  #pragma unroll
  for (int i = 0; i < 32; ++i) {
    const int idx = i * 256 + t;
    const int c = idx >> 6, d = idx & 63;
    Wl[c][d] = W[(long)(cb * 128 + c) * 1024 + h * 64 + d];
  }
  __syncthreads();
  const int c = t & 127, j0 = (t >> 7) * 32;
  float a[32];
  #pragma unroll
  for (int jj = 0; jj < 32; ++jj) a[jj] = 0.f;
  for (int d = 0; d < 64; ++d) {
    const float wv = Wl[c][d];
    #pragma unroll
    for (int jj = 0; jj < 32; ++jj) a[jj] += wv * Pl[d][j0 + jj];
  }
  #pragma unroll
  for (int jj = 0; jj < 32; ++jj)
    WqkvT[(long)(m * 1024 + h * 64 + j0 + jj) * 1024 + cb * 128 + c] = f2bf(a[jj]);
}

// Tiled transposes: WqkvT rows 2048..3071 = Wv^T ; WoT = Wo^T.
// grid: which(2) x rt(16) x ct(16) = 512 blocks; 64x64 f32 tile in LDS.
__global__ __launch_bounds__(256) void prep_vo(const float* __restrict__ Wv,
    const float* __restrict__ Wo, u16* __restrict__ WqkvT, u16* __restrict__ WoT) {
  __shared__ float til[64][65];
  const int bid = blockIdx.x;
  const int which = bid >> 8, rt = (bid >> 4) & 15, ct = bid & 15;
  const float* S = which ? Wo : Wv;          // S[in][out]
  const int t = threadIdx.x;
  const int j = t & 63;
  #pragma unroll
  for (int p = 0; p < 16; ++p) {
    const int i = p * 4 + (t >> 6);
    til[i][j] = S[(long)(rt * 64 + i) * 1024 + ct * 64 + j];
  }
  __syncthreads();
  u16* dst = which ? WoT : (WqkvT + (long)2048 * 1024);
  #pragma unroll
  for (int p = 0; p < 16; ++p) {
    const int i = p * 4 + (t >> 6);
    dst[(long)(ct * 64 + i) * 1024 + rt * 64 + j] = f2bf(til[j][i]);
  }
}

__global__ __launch_bounds__(256) void conv_x(const float* __restrict__ x,
                                              u16* __restrict__ xb) {
  const int idx = blockIdx.x * 256 + threadIdx.x;
  const float4* p = (const float4*)x + (long)idx * 2;
  const float4 a = p[0], b = p[1];
  u16x8 o;
  o[0] = f2bf(a.x); o[1] = f2bf(a.y); o[2] = f2bf(a.z); o[3] = f2bf(a.w);
  o[4] = f2bf(b.x); o[5] = f2bf(b.y); o[6] = f2bf(b.z); o[7] = f2bf(b.w);
  *((u16x8*)xb + idx) = o;
}

extern "C" void kernel_launch(void* const* d_in, const int* in_sizes, int n_in,
                              void* d_out, int out_size, void* d_ws, size_t ws_size,
                              hipStream_t stream) {
  const float* x    = (const float*)d_in[0];
  const float* mask = (const float*)d_in[1];
  const float* Wq   = (const float*)d_in[2];
  const float* Wk   = (const float*)d_in[3];
  const float* Wv   = (const float*)d_in[4];
  const float* Wo   = (const float*)d_in[5];
  const float* proj = (const float*)d_in[6];

  char* ws = (char*)d_ws;
  u16*  WqkvT = (u16*)(ws);                    // 3072x1024 bf16 = 6 MB
  u16*  WoT   = (u16*)(ws + 6291456);          // 1024x1024 bf16 = 2 MB
  u16*  xb    = (u16*)(ws + 8388608);          // 16384x1024 bf16 = 32 MB (reused as U)
  u16*  QKV   = (u16*)(ws + 41943040);         // 16384x3072 bf16 = 96 MB
  float* kvws = (float*)(ws + 142606336);      // 64*64*64 f32 = 1 MB
  float* ksws = (float*)(ws + 143654912);      // 64*64 f32 = 16 KB
  if (ws_size < (size_t)143671296) return;

  hipMemsetAsync(kvws, 0, 1064960, stream);
  prep_qk<<<256, 256, 0, stream>>>(Wq, Wk, proj, WqkvT);
  prep_vo<<<512, 256, 0, stream>>>(Wv, Wo, WqkvT, WoT);
  conv_x <<<8192, 256, 0, stream>>>(x, xb);
  gemm256<3072, 0><<<768, 512, 0, stream>>>(xb, WqkvT, (void*)QKV, mask);
  kv_kernel<<<512, 256, 0, stream>>>(QKV, kvws, ksws);
  u_kernel <<<4096, 256, 0, stream>>>(QKV, kvws, ksws, xb);
  gemm256<1024, 1><<<256, 512, 0, stream>>>(xb, WoT, d_out, nullptr);
}

// Round 6
// 277.066 us; speedup vs baseline: 1.3849x; 1.0182x over previous
//
#include <hip/hip_runtime.h>
#include <stdint.h>

#define TOKENS 16384
#define KDIM 1024
#define QKVN 3072

typedef unsigned short u16;
using bf16x8 = __attribute__((ext_vector_type(8))) __bf16;
using f32x4  = __attribute__((ext_vector_type(4))) float;
using u16x8  = __attribute__((ext_vector_type(8))) unsigned short;

__device__ inline u16 f2bf(float f) {
  union { float f; uint32_t u; } v; v.f = f;
  uint32_t u = v.u;
  return (u16)((u + 0x7FFFu + ((u >> 16) & 1u)) >> 16);
}
__device__ inline float bf2f(u16 s) {
  union { uint32_t u; float f; } v; v.u = ((uint32_t)s) << 16;
  return v.f;
}
__device__ inline void g2l16(const void* g, void* l) {
  __builtin_amdgcn_global_load_lds(
      (const __attribute__((address_space(1))) void*)g,
      (__attribute__((address_space(3))) void*)l, 16, 0, 0);
}

// Stage one 128x64 bf16 half-tile (16 KB): 512 threads x 2 global_load_lds x 16B.
// Linear LDS dest; global source pre-swizzled so swizzled ds_reads are conflict-free.
template<int LD>
__device__ inline void stage_half(const u16* __restrict__ g, u16* l, int t) {
  #pragma unroll
  for (int i = 0; i < 2; ++i) {
    const int ch = i * 512 + t;          // 0..1023 chunks of 16B
    const int row = ch >> 3;             // 0..127
    const int cc = (ch & 7) ^ (row & 7); // source chunk pre-swizzle
    g2l16(g + (long)row * LD + cc * 8, (char*)l + ch * 16);
  }
}

// Fragment loads from a 128x64 half (16 KB) at BASE (compile-time array expr);
// XOR-swizzled ds_read_b128. DST[x][kh] = k-half kh.
#define LDA_H(DST, BASE) do { \
  _Pragma("unroll") \
  for (int mi = 0; mi < 4; ++mi) { \
    const int row = wm*64 + mi*16 + rl; \
    const char* p = (const char*)(BASE) + row*128; \
    const int sw = (row & 7) << 4; \
    DST[mi][0] = *(const bf16x8*)(p + ((kg*16) ^ sw)); \
    DST[mi][1] = *(const bf16x8*)(p + ((64 + kg*16) ^ sw)); \
  } \
} while (0)

#define LDB_H(DST, BASE) do { \
  _Pragma("unroll") \
  for (int ni = 0; ni < 2; ++ni) { \
    const int row = wn*32 + ni*16 + rl; \
    const char* p = (const char*)(BASE) + row*128; \
    const int sw = (row & 7) << 4; \
    DST[ni][0] = *(const bf16x8*)(p + ((kg*16) ^ sw)); \
    DST[ni][1] = *(const bf16x8*)(p + ((64 + kg*16) ^ sw)); \
  } \
} while (0)

// 16 MFMA quadrant burst; kh-major so the 8 MFMAs in each wavefront of the
// burst are independent (no same-acc back-to-back pairs).
#define MFMAQ(MH, NH, AV, BV) do { \
  __builtin_amdgcn_s_setprio(1); \
  _Pragma("unroll") \
  for (int kh = 0; kh < 2; ++kh) \
    _Pragma("unroll") \
    for (int mi = 0; mi < 4; ++mi) \
      _Pragma("unroll") \
      for (int ni = 0; ni < 2; ++ni) \
        acc[(MH)*4+mi][(NH)*2+ni] = __builtin_amdgcn_mfma_f32_16x16x32_bf16( \
            AV[mi][kh], BV[ni][kh], acc[(MH)*4+mi][(NH)*2+ni], 0, 0, 0); \
  __builtin_amdgcn_s_setprio(0); \
} while (0)

#define LGKM0 do { \
  asm volatile("s_waitcnt lgkmcnt(0)" ::: "memory"); \
  __builtin_amdgcn_sched_barrier(0); \
} while (0)
#define LGKM_PRE(N) asm volatile("s_waitcnt lgkmcnt(" #N ")" ::: "memory")
#define VMC(N) asm volatile("s_waitcnt vmcnt(" #N ")" ::: "memory")
#define BAR() __builtin_amdgcn_s_barrier()

// C = A(16384 x 1024, bf16, ld ALD) @ B^T (B stored N x 1024 bf16 rm).
// 256x256 tile, 8 waves (2Mx4N), m201-faithful 8-phase / 2-K-chunk iteration:
// reads {12,4,8,0} per phase (this phase's operands, lgkmcnt(0) before MFMA),
// 1 half-tile staged per phase into the slot read 1 phase earlier,
// vmcnt(6) only at phases 4/8. Persistent: each block runs NT output tiles.
// EPI 0: QKV epilogue (phi cols<2048, mask on K cols), bf16 C (ld 3072), aux=mask
// EPI 1: plain fp32 C (ld NTOT)
template<int NTOT, int EPI, int ALD, int NT, int PERB>
__global__ __launch_bounds__(512, 2) void gemm256(
    const u16* __restrict__ A, const u16* __restrict__ Bm,
    void* __restrict__ C, const float* __restrict__ aux) {
  __shared__ u16 As[2][2][8192];   // [kchunk parity][row-half][128 x 64]
  __shared__ u16 Bs[2][2][8192];
  const int t = threadIdx.x;
  const int l = t & 63;
  const int w = t >> 6;
  const int rl = l & 15, kg = l >> 4;
  const int wm = w >> 2, wn = w & 3;      // 2M x 4N waves
  constexpr int nbn = NTOT / 256;
  constexpr int nwg = 64 * nbn;           // total output tiles
  constexpr int GRID = nwg / NT;          // blocks launched
  constexpr int KC = NT * 16;             // K-chunks (64 wide) per block
  constexpr int IT = KC / 2;              // unrolled iterations
  static_assert(nwg % 8 == 0, "bijective xcd swizzle");
  const int bid = blockIdx.x;

  auto tcoord = [&](int ot, long& tar, long& tbr) {
    const int gt = ot * GRID + bid;
    const int swz = (gt & 7) * (nwg / 8) + (gt >> 3);
    tar = (long)(swz / nbn) * 256;
    tbr = (long)(swz % nbn) * 256;
  };
  auto asrc = [&](int ch) {
    long ta, tb; tcoord(ch >> 4, ta, tb);
    return A + ta * ALD + (ch & 15) * 64;
  };
  auto bsrc = [&](int ch) {
    long ta, tb; tcoord(ch >> 4, ta, tb);
    return Bm + (PERB ? (ta >> 12) * 1048576 : 0) + tb * 1024 + (ch & 15) * 64;
  };

  f32x4 acc[8][4];
  #pragma unroll
  for (int i = 0; i < 8; ++i)
    #pragma unroll
    for (int j = 0; j < 4; ++j)
      acc[i][j] = (f32x4){0.f, 0.f, 0.f, 0.f};

  bf16x8 af[4][2], b0[2][2], b1[2][2];

  auto epilogue = [&](int ot) {
    long ar0, br0; tcoord(ot, ar0, br0);
    #pragma unroll
    for (int mh = 0; mh < 2; ++mh)
      #pragma unroll
      for (int mi = 0; mi < 4; ++mi)
        #pragma unroll
        for (int j = 0; j < 4; ++j) {
          const long row = ar0 + mh*128 + wm*64 + mi*16 + kg*4 + j;
          float rs = 0.f;
          if (EPI == 0) rs = aux[row];            // mask[token]
          #pragma unroll
          for (int nh = 0; nh < 2; ++nh)
            #pragma unroll
            for (int ni = 0; ni < 2; ++ni) {
              const long col = br0 + nh*128 + wn*32 + ni*16 + rl;
              float v = acc[mh*4+mi][nh*2+ni][j];
              if (EPI == 0) {
                if (col < 2048) {                  // Q or K: phi = elu(x)+1
                  v = (v > 0.f) ? (v + 1.f) : __expf(v);
                  if (col >= 1024) v *= rs;        // K: * mask[token]
                }
                ((u16*)C)[row * QKVN + col] = f2bf(v);
              } else {
                ((float*)C)[row * NTOT + col] = v;
              }
            }
        }
    #pragma unroll
    for (int i = 0; i < 8; ++i)
      #pragma unroll
      for (int j = 0; j < 4; ++j)
        acc[i][j] = (f32x4){0.f, 0.f, 0.f, 0.f};
  };

  // Prologue: chunk0 all 4 halves, chunk1 A0,B0,B1 (A1 staged at iter0 ph1).
  {
    const u16* A0s = asrc(0); const u16* B0s = bsrc(0);
    const u16* A1s = asrc(1); const u16* B1s = bsrc(1);
    stage_half<ALD >(A0s,             As[0][0], t);
    stage_half<1024>(B0s,             Bs[0][0], t);
    stage_half<1024>(B0s + 128*1024,  Bs[0][1], t);
    stage_half<ALD >(A0s + 128*ALD,   As[0][1], t);
    stage_half<ALD >(A1s,             As[1][0], t);
    stage_half<1024>(B1s,             Bs[1][0], t);
    stage_half<1024>(B1s + 128*1024,  Bs[1][1], t);
    VMC(6);            // chunk0 fully landed; chunk1's 3 halves in flight
    BAR();
  }

  for (int i = 0; i < IT; ++i) {
    const int e = (2*i + 2 < KC) ? 2*i + 2 : KC - 1;   // even chunk -> parity 0
    const int o = (2*i + 3 < KC) ? 2*i + 3 : KC - 1;   // odd chunk  -> parity 1
    const u16* Ao1 = asrc(2*i + 1);
    const u16* Ae = asrc(e); const u16* Be = bsrc(e);
    const u16* Ao = asrc(o); const u16* Bo = bsrc(o);

    // ph1 Q00 (chunk 2i): stage A1(2i+1) -> As[1][1]
    LDA_H(af, As[0][0]); LDB_H(b0, Bs[0][0]);
    stage_half<ALD>(Ao1 + 128*ALD, As[1][1], t);
    LGKM_PRE(8);
    BAR(); LGKM0;
    MFMAQ(0, 0, af, b0);
    BAR();
    // ph2 Q01: stage A0(e) -> As[0][0] (read-done ph1)
    LDB_H(b1, Bs[0][1]);
    stage_half<ALD>(Ae, As[0][0], t);
    BAR(); LGKM0;
    MFMAQ(0, 1, af, b1);
    BAR();
    // ph3 Q10: stage B0(e) -> Bs[0][0] (read-done ph1)
    LDA_H(af, As[0][1]);
    stage_half<1024>(Be, Bs[0][0], t);
    BAR(); LGKM0;
    MFMAQ(1, 0, af, b0);
    BAR();
    // ph4 Q11: stage B1(e) -> Bs[0][1] (read-done ph2); counted vmcnt
    stage_half<1024>(Be + 128*1024, Bs[0][1], t);
    BAR();
    MFMAQ(1, 1, af, b1);
    VMC(6);
    BAR();
    // ph5 Q00 (chunk 2i+1): stage A1(e) -> As[0][1] (read-done ph3)
    LDA_H(af, As[1][0]); LDB_H(b0, Bs[1][0]);
    stage_half<ALD>(Ae + 128*ALD, As[0][1], t);
    LGKM_PRE(8);
    BAR(); LGKM0;
    MFMAQ(0, 0, af, b0);
    BAR();
    // ph6 Q01: stage A0(o) -> As[1][0] (read-done ph5)
    LDB_H(b1, Bs[1][1]);
    stage_half<ALD>(Ao, As[1][0], t);
    BAR(); LGKM0;
    MFMAQ(0, 1, af, b1);
    BAR();
    // ph7 Q10: stage B0(o) -> Bs[1][0] (read-done ph5)
    LDA_H(af, As[1][1]);
    stage_half<1024>(Bo, Bs[1][0], t);
    BAR(); LGKM0;
    MFMAQ(1, 0, af, b0);
    BAR();
    // ph8 Q11: stage B1(o) -> Bs[1][1] (read-done ph6); counted vmcnt
    stage_half<1024>(Bo + 128*1024, Bs[1][1], t);
    BAR();
    MFMAQ(1, 1, af, b1);
    VMC(6);
    BAR();

    if ((i & 7) == 7) epilogue(i >> 3);
  }
  VMC(0);   // drain DMA before LDS is released
}

// kv[bh][d][e] = sum_n K[n][d] * V[n][e];  ksum[bh][d] = sum_n K[n][d]
__global__ __launch_bounds__(256) void kv_kernel(const u16* __restrict__ QKV,
    float* __restrict__ kvws, float* __restrict__ ksws) {
  __shared__ u16 Kl[32 * 64];
  __shared__ u16 Vl[32 * 64];
  const int t = threadIdx.x;
  const int l = t & 63, w = t >> 6;
  const int rl = l & 15, kg = l >> 4;
  const int bid = blockIdx.x;
  const int bh = bid >> 3, ns = bid & 7;
  const int b = bh >> 4, h = bh & 15;
  const long tok0 = (long)b * 4096 + ns * 512;

  f32x4 acc[4];
  #pragma unroll
  for (int i = 0; i < 4; ++i) acc[i] = (f32x4){0.f, 0.f, 0.f, 0.f};
  float ks = 0.f;
  const int srow = t >> 3, scc = t & 7;

  for (int it = 0; it < 16; ++it) {
    const long tb = tok0 + it * 32;
    g2l16(QKV + (tb + srow) * QKVN + 1024 + h * 64 + scc * 8, (char*)Kl + t * 16);
    g2l16(QKV + (tb + srow) * QKVN + 2048 + h * 64 + scc * 8, (char*)Vl + t * 16);
    __syncthreads();
    union { u16x8 u; bf16x8 v; } au, bu;
    #pragma unroll
    for (int j = 0; j < 8; ++j) au.u[j] = Kl[(kg * 8 + j) * 64 + w * 16 + rl];
    #pragma unroll
    for (int ni = 0; ni < 4; ++ni) {
      #pragma unroll
      for (int j = 0; j < 8; ++j) bu.u[j] = Vl[(kg * 8 + j) * 64 + ni * 16 + rl];
      acc[ni] = __builtin_amdgcn_mfma_f32_16x16x32_bf16(au.v, bu.v, acc[ni], 0, 0, 0);
    }
    #pragma unroll
    for (int r = 0; r < 8; ++r) ks += bf2f(Kl[(w * 8 + r) * 64 + (t & 63)]);
    __syncthreads();
  }
  float* kvb = kvws + bh * 4096;
  #pragma unroll
  for (int ni = 0; ni < 4; ++ni)
    #pragma unroll
    for (int j = 0; j < 4; ++j) {
      const int d = w * 16 + kg * 4 + j;
      const int e = ni * 16 + rl;
      atomicAdd(&kvb[d * 64 + e], acc[ni][j]);
    }
  atomicAdd(&ksws[bh * 64 + (t & 63)], ks);
}

// Per-head normalize Q in place:
// Q[n][h*64+d] /= (sum_d' Q[n][h*64+d'] * ksum[b*16+h][d'] + 1e-6)
// block = 16 tokens x 16 heads; grid = 1024
__global__ __launch_bounds__(256) void scale_q(u16* __restrict__ QKV,
    const float* __restrict__ ksws) {
  __shared__ float ksl[1024];
  const int bid = blockIdx.x, t = threadIdx.x;
  const int n0 = bid * 16;
  const int b = n0 >> 12;
  #pragma unroll
  for (int i = 0; i < 4; ++i) ksl[i * 256 + t] = ksws[b * 1024 + i * 256 + t];
  __syncthreads();
  const int h = t & 15, ti = t >> 4;
  u16* qp = QKV + (long)(n0 + ti) * QKVN + h * 64;
  u16x8 v[8];
  float norm = 1e-6f;
  #pragma unroll
  for (int i = 0; i < 8; ++i) {
    v[i] = *(const u16x8*)(qp + i * 8);
    #pragma unroll
    for (int j = 0; j < 8; ++j) norm += bf2f(v[i][j]) * ksl[h * 64 + i * 8 + j];
  }
  const float inv = 1.0f / norm;
  #pragma unroll
  for (int i = 0; i < 8; ++i) {
    u16x8 o;
    #pragma unroll
    for (int j = 0; j < 8; ++j) o[j] = f2bf(bf2f(v[i][j]) * inv);
    *(u16x8*)(qp + i * 8) = o;
  }
}

// W2T[b][o][h*64+d] = sum_e kv[b*16+h][d][e] * WoT[o][h*64+e]
// grid: 256 = bh(64) x os(4); thread owns one o row.
__global__ __launch_bounds__(256) void w2_kernel(const float* __restrict__ kvws,
    const u16* __restrict__ WoT, u16* __restrict__ W2T) {
  __shared__ float kvl[64][64];
  const int bid = blockIdx.x, t = threadIdx.x;
  const int bh = bid >> 2, os = bid & 3;
  const int b = bh >> 4, h = bh & 15;
  const float* kvb = kvws + bh * 4096;
  #pragma unroll
  for (int i = 0; i < 16; ++i) ((float*)kvl)[i * 256 + t] = kvb[i * 256 + t];
  __syncthreads();
  const int o = os * 256 + t;
  float wo[64];
  const u16* wr = WoT + (long)o * 1024 + h * 64;
  #pragma unroll
  for (int i = 0; i < 8; ++i) {
    u16x8 v = *(const u16x8*)(wr + i * 8);
    #pragma unroll
    for (int j = 0; j < 8; ++j) wo[i * 8 + j] = bf2f(v[j]);
  }
  u16* out = W2T + (long)b * 1048576 + (long)o * 1024 + h * 64;
  for (int d = 0; d < 64; ++d) {
    float s = 0.f;
    #pragma unroll
    for (int e = 0; e < 64; ++e) s += wo[e] * kvl[d][e];
    out[d] = f2bf(s);
  }
}

// WqkvT rows 0..2047 = (W{q,k} @ blockdiag(proj))^T. LDS-staged, coalesced.
__global__ __launch_bounds__(256) void prep_qk(const float* __restrict__ Wq,
    const float* __restrict__ Wk, const float* __restrict__ proj,
    u16* __restrict__ WqkvT) {
  __shared__ float Wl[128][65];
  __shared__ float Pl[64][65];
  const int bid = blockIdx.x;
  const int m = bid >> 7, h = (bid >> 3) & 15, cb = bid & 7;
  const float* W = m ? Wk : Wq;
  const int t = threadIdx.x;
  #pragma unroll
  for (int i = 0; i < 16; ++i) {
    const int idx = i * 256 + t;
    Pl[idx >> 6][idx & 63] = proj[idx];
  }
  #pragma unroll
  for (int i = 0; i < 32; ++i) {
    const int idx = i * 256 + t;
    const int c = idx >> 6, d = idx & 63;
    Wl[c][d] = W[(long)(cb * 128 + c) * 1024 + h * 64 + d];
  }
  __syncthreads();
  const int c = t & 127, j0 = (t >> 7) * 32;
  float a[32];
  #pragma unroll
  for (int jj = 0; jj < 32; ++jj) a[jj] = 0.f;
  for (int d = 0; d < 64; ++d) {
    const float wv = Wl[c][d];
    #pragma unroll
    for (int jj = 0; jj < 32; ++jj) a[jj] += wv * Pl[d][j0 + jj];
  }
  #pragma unroll
  for (int jj = 0; jj < 32; ++jj)
    WqkvT[(long)(m * 1024 + h * 64 + j0 + jj) * 1024 + cb * 128 + c] = f2bf(a[jj]);
}

// Tiled transposes: WqkvT rows 2048..3071 = Wv^T ; WoT = Wo^T.
__global__ __launch_bounds__(256) void prep_vo(const float* __restrict__ Wv,
    const float* __restrict__ Wo, u16* __restrict__ WqkvT, u16* __restrict__ WoT) {
  __shared__ float til[64][65];
  const int bid = blockIdx.x;
  const int which = bid >> 8, rt = (bid >> 4) & 15, ct = bid & 15;
  const float* S = which ? Wo : Wv;          // S[in][out]
  const int t = threadIdx.x;
  const int j = t & 63;
  #pragma unroll
  for (int p = 0; p < 16; ++p) {
    const int i = p * 4 + (t >> 6);
    til[i][j] = S[(long)(rt * 64 + i) * 1024 + ct * 64 + j];
  }
  __syncthreads();
  u16* dst = which ? WoT : (WqkvT + (long)2048 * 1024);
  #pragma unroll
  for (int p = 0; p < 16; ++p) {
    const int i = p * 4 + (t >> 6);
    dst[(long)(ct * 64 + i) * 1024 + rt * 64 + j] = f2bf(til[j][i]);
  }
}

__global__ __launch_bounds__(256) void conv_x(const float* __restrict__ x,
                                              u16* __restrict__ xb) {
  const int idx = blockIdx.x * 256 + threadIdx.x;
  const float4* p = (const float4*)x + (long)idx * 2;
  const float4 a = p[0], b = p[1];
  u16x8 o;
  o[0] = f2bf(a.x); o[1] = f2bf(a.y); o[2] = f2bf(a.z); o[3] = f2bf(a.w);
  o[4] = f2bf(b.x); o[5] = f2bf(b.y); o[6] = f2bf(b.z); o[7] = f2bf(b.w);
  *((u16x8*)xb + idx) = o;
}

extern "C" void kernel_launch(void* const* d_in, const int* in_sizes, int n_in,
                              void* d_out, int out_size, void* d_ws, size_t ws_size,
                              hipStream_t stream) {
  const float* x    = (const float*)d_in[0];
  const float* mask = (const float*)d_in[1];
  const float* Wq   = (const float*)d_in[2];
  const float* Wk   = (const float*)d_in[3];
  const float* Wv   = (const float*)d_in[4];
  const float* Wo   = (const float*)d_in[5];
  const float* proj = (const float*)d_in[6];

  char* ws = (char*)d_ws;
  u16*  WqkvT = (u16*)(ws);                    // 3072x1024 bf16 = 6 MB
  u16*  WoT   = (u16*)(ws + 6291456);          // 1024x1024 bf16 = 2 MB
  u16*  xb    = (u16*)(ws + 8388608);          // 16384x1024 bf16 = 32 MB
  u16*  QKV   = (u16*)(ws + 41943040);         // 16384x3072 bf16 = 96 MB
  float* kvws = (float*)(ws + 142606336);      // 64*64*64 f32 = 1 MB
  float* ksws = (float*)(ws + 143654912);      // 64*64 f32 = 16 KB
  // xb is dead after the QKV GEMM: reuse its region for W2T (4 x 1024 x 1024 bf16 = 8 MB)
  u16*  W2T  = (u16*)(ws + 8388608);
  if (ws_size < (size_t)143671296) return;

  hipMemsetAsync(kvws, 0, 1064960, stream);
  prep_qk<<<256, 256, 0, stream>>>(Wq, Wk, proj, WqkvT);
  prep_vo<<<512, 256, 0, stream>>>(Wv, Wo, WqkvT, WoT);
  conv_x <<<8192, 256, 0, stream>>>(x, xb);
  gemm256<3072, 0, 1024, 3, 0><<<256, 512, 0, stream>>>(xb, WqkvT, (void*)QKV, mask);
  kv_kernel<<<512, 256, 0, stream>>>(QKV, kvws, ksws);
  scale_q<<<1024, 256, 0, stream>>>((u16*)QKV, ksws);
  w2_kernel<<<256, 256, 0, stream>>>(kvws, WoT, W2T);
  gemm256<1024, 1, 3072, 1, 1><<<256, 512, 0, stream>>>(QKV, W2T, d_out, nullptr);
}